// Round 6
// baseline (1070.431 us; speedup 1.0000x reference)
//
#include <hip/hip_runtime.h>
#include <math.h>

#define Bb   4
#define Ss   16
#define Nn   2048
#define Ff   32
#define Ee   16384
#define EFf  8
#define Hh   64
#define HB2  32
#define E2c  (Ee + Nn)          // 18432
#define RTOT (Bb*Ss*Nn)         // 131072
#define Mm   (Ss*Nn)            // 32768

__device__ __forceinline__ float sigf(float x) { return 1.f / (1.f + __expf(-x)); }
__device__ __forceinline__ float tanhfast(float x) { return 2.f / (1.f + __expf(-2.f * x)) - 1.f; }

// 64-lane sum, all-DPP (zero DS): quad xor1/xor2, row_ror4/8, bcast15/31,
// total lands in lane 63 -> readlane. Returns wave-uniform value.
__device__ __forceinline__ float rsum64u(float v) {
  int x;
  x = __builtin_amdgcn_update_dpp(0, __float_as_int(v), 0xB1, 0xF, 0xF, true);   // quad_perm xor1
  v += __int_as_float(x);
  x = __builtin_amdgcn_update_dpp(0, __float_as_int(v), 0x4E, 0xF, 0xF, true);   // quad_perm xor2
  v += __int_as_float(x);
  x = __builtin_amdgcn_update_dpp(0, __float_as_int(v), 0x124, 0xF, 0xF, true);  // row_ror:4
  v += __int_as_float(x);
  x = __builtin_amdgcn_update_dpp(0, __float_as_int(v), 0x128, 0xF, 0xF, true);  // row_ror:8
  v += __int_as_float(x);
  x = __builtin_amdgcn_update_dpp(0, __float_as_int(v), 0x142, 0xF, 0xF, true);  // row_bcast:15
  v += __int_as_float(x);
  x = __builtin_amdgcn_update_dpp(0, __float_as_int(v), 0x143, 0xF, 0xF, true);  // row_bcast:31
  v += __int_as_float(x);
  return __int_as_float(__builtin_amdgcn_readlane(__float_as_int(v), 63));
}

// ---------------------------------------------------------------------------
__global__ __launch_bounds__(256) void k_loop_accum(
    const int* __restrict__ ei, const float* __restrict__ ea,
    float* __restrict__ cntF, float* __restrict__ loopA) {
  int idx = blockIdx.x * 256 + threadIdx.x;
  int e = idx >> 3, j = idx & 7;
  int d = ei[Ee + e];
  atomicAdd(&loopA[d * EFf + j], ea[idx]);
  if (j == 0) atomicAdd(&cntF[d], 1.0f);
}

__global__ __launch_bounds__(256) void k_loop_div(
    float* __restrict__ loopA, const float* __restrict__ cntF) {
  int idx = blockIdx.x * 256 + threadIdx.x;
  loopA[idx] /= fmaxf(cntF[idx >> 3], 1.0f);
}

// ---------------------------------------------------------------------------
__global__ __launch_bounds__(256) void k_scan(
    const float* __restrict__ cntF, int* __restrict__ offs) {
  __shared__ int partial[256];
  int tid = threadIdx.x;
  int base = tid * 8;
  int vals[8];
  int s = 0;
  for (int i = 0; i < 8; ++i) {
    int c = (int)cntF[base + i] + 1;
    vals[i] = c;
    s += c;
  }
  partial[tid] = s;
  __syncthreads();
  for (int off = 1; off < 256; off <<= 1) {
    int v = partial[tid];
    int add = (tid >= off) ? partial[tid - off] : 0;
    __syncthreads();
    partial[tid] = v + add;
    __syncthreads();
  }
  int run = (tid == 0) ? 0 : partial[tid - 1];
  for (int i = 0; i < 8; ++i) {
    offs[base + i] = run;
    run += vals[i];
  }
  if (tid == 255) offs[Nn] = run;
}

__global__ __launch_bounds__(256) void k_scatter(
    const int* __restrict__ ei, const int* __restrict__ offs,
    int* __restrict__ fillI, int* __restrict__ posOf, int* __restrict__ srcA) {
  int e = blockIdx.x * 256 + threadIdx.x;
  if (e >= E2c) return;
  int d = (e < Ee) ? ei[Ee + e] : (e - Ee);
  int s = (e < Ee) ? ei[e]      : (e - Ee);
  int pos = offs[d] + atomicAdd(&fillI[d], 1);
  posOf[e] = pos;
  srcA[pos] = s;
}

// ---------------------------------------------------------------------------
__global__ __launch_bounds__(256) void k_wtr(
    const float* __restrict__ Wih, const float* __restrict__ Whh,
    float* __restrict__ WT) {
  int idx = blockIdx.x * 256 + threadIdx.x;   // 2*64*384
  int l = idx / (64 * 384);
  int k = (idx / 384) & 63;
  int j = idx % 384;
  float v = (j < 192) ? Wih[((size_t)l * 192 + j) * 64 + k]
                      : Whh[((size_t)l * 192 + (j - 192)) * 64 + k];
  WT[idx] = v;
}

// ---------------------------------------------------------------------------
__global__ __launch_bounds__(256) void k_ep(
    const float* __restrict__ ea, const float* __restrict__ loopA,
    const float* __restrict__ We, const int* __restrict__ posOf,
    float* __restrict__ EPc) {
  __shared__ float wlds[EFf * Hh];
  int tid = threadIdx.x;
  if (tid < EFf * Hh) wlds[tid] = We[tid];
  if (tid + 256 < EFf * Hh) wlds[tid + 256] = We[tid + 256];
  __syncthreads();
  int idx = blockIdx.x * 256 + tid;
  int e = idx >> 6, j = idx & 63;
  const float* a = (e < Ee) ? (ea + (size_t)e * EFf) : (loopA + (size_t)(e - Ee) * EFf);
  float acc = 0.f;
#pragma unroll
  for (int k = 0; k < EFf; ++k) acc += a[k] * wlds[k * Hh + j];
  EPc[(((size_t)posOf[e]) << 6) + j] = acc;
}

// ---------------------------------------------------------------------------
// proj: thread = 8 rows x 8 cols. W tile in LDS (uniform b128 broadcast),
// 8:1 FMA:DS. grid (RTOT/2048, 8).
// ---------------------------------------------------------------------------
__global__ __launch_bounds__(256) void k_proj(
    const float* __restrict__ X, const float* __restrict__ Wp,
    const float* __restrict__ bp, float* __restrict__ Out) {
  __shared__ float w[32 * 8];
  int tid = threadIdx.x;
  int j0 = blockIdx.y << 3;
  if (tid < 256) {
    int k = tid >> 3, jj = tid & 7;
    w[tid] = Wp[(k << 6) + j0 + jj];
  }
  __syncthreads();
  int rbase = (blockIdx.x << 11) + tid;
  float acc[8][8];
  float bv[8];
#pragma unroll
  for (int jj = 0; jj < 8; ++jj) bv[jj] = bp[j0 + jj];
#pragma unroll
  for (int i = 0; i < 8; ++i)
#pragma unroll
    for (int jj = 0; jj < 8; ++jj) acc[i][jj] = bv[jj];
#pragma unroll 1
  for (int kc = 0; kc < 8; ++kc) {
    float4 a[8];
#pragma unroll
    for (int i = 0; i < 8; ++i)
      a[i] = *(const float4*)(X + (size_t)(rbase + (i << 8)) * 32 + 4 * kc);
#pragma unroll
    for (int q = 0; q < 4; ++q) {
      int k = 4 * kc + q;
      float4 w0 = *(const float4*)(w + (k << 3));
      float4 w1 = *(const float4*)(w + (k << 3) + 4);
#pragma unroll
      for (int i = 0; i < 8; ++i) {
        float xv = ((const float*)&a[i])[q];
        acc[i][0] = fmaf(xv, w0.x, acc[i][0]);
        acc[i][1] = fmaf(xv, w0.y, acc[i][1]);
        acc[i][2] = fmaf(xv, w0.z, acc[i][2]);
        acc[i][3] = fmaf(xv, w0.w, acc[i][3]);
        acc[i][4] = fmaf(xv, w1.x, acc[i][4]);
        acc[i][5] = fmaf(xv, w1.y, acc[i][5]);
        acc[i][6] = fmaf(xv, w1.z, acc[i][6]);
        acc[i][7] = fmaf(xv, w1.w, acc[i][7]);
      }
    }
  }
#pragma unroll
  for (int i = 0; i < 8; ++i) {
    float* op = Out + ((size_t)(rbase + (i << 8)) << 6) + j0;
    *(float4*)(op)     = make_float4(acc[i][0], acc[i][1], acc[i][2], acc[i][3]);
    *(float4*)(op + 4) = make_float4(acc[i][4], acc[i][5], acc[i][6], acc[i][7]);
  }
}

// ---------------------------------------------------------------------------
// Fused XL/XR: thread = 8 rows x 8 cols, both mats. Per k: 4 uniform b128 vs
// 128 FMA = 8:1. grid (RTOT/2048, 8) -> row-chunk fastest so all col-blocks
// of a chunk share an XCD (blockid%8) for L2 reuse of X.
// ---------------------------------------------------------------------------
__global__ __launch_bounds__(256) void k_xlr(
    const float* __restrict__ X,
    const float* __restrict__ Wl_, const float* __restrict__ bl_,
    const float* __restrict__ Wr_, const float* __restrict__ br_,
    float* __restrict__ XL, float* __restrict__ XR) {
  __shared__ float wl[64 * 8], wr[64 * 8];
  int tid = threadIdx.x;
  int j0 = blockIdx.y << 3;
  for (int idx = tid; idx < 512; idx += 256) {
    int k = idx >> 3, jj = idx & 7;
    wl[idx] = Wl_[(k << 6) + j0 + jj];
    wr[idx] = Wr_[(k << 6) + j0 + jj];
  }
  __syncthreads();
  int rbase = (blockIdx.x << 11) + tid;
  float accL[8][8], accR[8][8];
#pragma unroll
  for (int jj = 0; jj < 8; ++jj) {
    float bL = bl_[j0 + jj], bR = br_[j0 + jj];
#pragma unroll
    for (int i = 0; i < 8; ++i) { accL[i][jj] = bL; accR[i][jj] = bR; }
  }
#pragma unroll 1
  for (int kc = 0; kc < 16; ++kc) {
    float4 a[8];
#pragma unroll
    for (int i = 0; i < 8; ++i)
      a[i] = *(const float4*)(X + ((size_t)(rbase + (i << 8)) << 6) + 4 * kc);
#pragma unroll
    for (int q = 0; q < 4; ++q) {
      int k = 4 * kc + q;
      float4 l0 = *(const float4*)(wl + (k << 3));
      float4 l1 = *(const float4*)(wl + (k << 3) + 4);
      float4 r0 = *(const float4*)(wr + (k << 3));
      float4 r1 = *(const float4*)(wr + (k << 3) + 4);
#pragma unroll
      for (int i = 0; i < 8; ++i) {
        float xv = ((const float*)&a[i])[q];
        accL[i][0] = fmaf(xv, l0.x, accL[i][0]);
        accL[i][1] = fmaf(xv, l0.y, accL[i][1]);
        accL[i][2] = fmaf(xv, l0.z, accL[i][2]);
        accL[i][3] = fmaf(xv, l0.w, accL[i][3]);
        accL[i][4] = fmaf(xv, l1.x, accL[i][4]);
        accL[i][5] = fmaf(xv, l1.y, accL[i][5]);
        accL[i][6] = fmaf(xv, l1.z, accL[i][6]);
        accL[i][7] = fmaf(xv, l1.w, accL[i][7]);
        accR[i][0] = fmaf(xv, r0.x, accR[i][0]);
        accR[i][1] = fmaf(xv, r0.y, accR[i][1]);
        accR[i][2] = fmaf(xv, r0.z, accR[i][2]);
        accR[i][3] = fmaf(xv, r0.w, accR[i][3]);
        accR[i][4] = fmaf(xv, r1.x, accR[i][4]);
        accR[i][5] = fmaf(xv, r1.y, accR[i][5]);
        accR[i][6] = fmaf(xv, r1.z, accR[i][6]);
        accR[i][7] = fmaf(xv, r1.w, accR[i][7]);
      }
    }
  }
#pragma unroll
  for (int i = 0; i < 8; ++i) {
    size_t ob = ((size_t)(rbase + (i << 8)) << 6) + j0;
    *(float4*)(XL + ob)     = make_float4(accL[i][0], accL[i][1], accL[i][2], accL[i][3]);
    *(float4*)(XL + ob + 4) = make_float4(accL[i][4], accL[i][5], accL[i][6], accL[i][7]);
    *(float4*)(XR + ob)     = make_float4(accR[i][0], accR[i][1], accR[i][2], accR[i][3]);
    *(float4*)(XR + ob + 4) = make_float4(accR[i][4], accR[i][5], accR[i][6], accR[i][7]);
  }
}

// ---------------------------------------------------------------------------
// GATv2: wave per (g,d), lane = h. DS-free inner loop: DPP reduce + readlane
// broadcast of src offsets. 8-wide masked chunks.
// ---------------------------------------------------------------------------
__global__ __launch_bounds__(256) void k_gat(
    const float* __restrict__ XL, float* __restrict__ XR_HG,
    const float* __restrict__ EPc, const int* __restrict__ offs,
    const int* __restrict__ srcA,
    const float* __restrict__ att, const float* __restrict__ gbl) {
  int gw = (blockIdx.x * 256 + threadIdx.x) >> 6;
  int lane = threadIdx.x & 63;
  int g = gw >> 11;
  int d = gw & (Nn - 1);
  float attv = att[lane];
  float gbv = gbl[lane];
  size_t rowbase = ((size_t)gw) << 6;
  float xr = XR_HG[rowbase + lane];
  int p0 = offs[d], p1 = offs[d + 1];
  int nE = p1 - p0;
  int nE4 = nE < 64 ? nE : 64;
  int soff = 0;
  if (lane < nE4) soff = srcA[p0 + lane] << 8;           // byte offset of src row
  const char* XLg = (const char*)(XL + (((size_t)g * Nn) << 6)) + (lane << 2);
  const char* EPp = (const char*)(EPc + (((size_t)p0) << 6)) + (lane << 2);
  float Ssum = 0.f, acc = 0.f;
  int nCh = (nE4 + 7) >> 3;
  for (int c = 0; c < nCh; ++c) {
    int p = c << 3;
    float xl[8], vv[8];
#pragma unroll
    for (int u = 0; u < 8; ++u) {
      int pu = p + u;
      int pc = pu < nE4 ? pu : nE4 - 1;                  // clamp (masked later)
      int so = __builtin_amdgcn_readlane(soff, pc);      // uniform, no DS
      xl[u] = *(const float*)(XLg + so);
      float ep = *(const float*)(EPp + (pc << 8));
      float m = xl[u] + xr + ep;
      m = fmaxf(m, 0.2f * m);                            // leaky_relu(0.2)
      vv[u] = m * attv;
    }
#pragma unroll
    for (int u = 0; u < 8; ++u) vv[u] = rsum64u(vv[u]);
#pragma unroll
    for (int u = 0; u < 8; ++u) {
      float v = (p + u < nE4) ? vv[u] : -1e30f;
      float w = __expf(v);
      Ssum += w;
      acc = fmaf(w, xl[u], acc);
    }
  }
  for (int p = 64; p < nE; ++p) {                        // pathological tail
    int s = srcA[p0 + p];
    float xlv = *(const float*)(XLg + (s << 8));
    float ep = *(const float*)(EPp + (p << 8));
    float m = xlv + xr + ep; m = fmaxf(m, 0.2f * m);
    float w = __expf(rsum64u(m * attv));
    Ssum += w; acc = fmaf(w, xlv, acc);
  }
  XR_HG[rowbase + lane] = acc / Ssum + gbv;
}

// ---------------------------------------------------------------------------
// Per-t fused GRU: thread = 8 rows x 4 h-cols. Fused accumulators:
// aR = ir+hr, aZ = iz+hz, aNi = inn, aNh = hn  -> 128 acc VGPRs.
// Per k: 6 uniform b128 (48cy) vs 192 FMA (384cy) = 8:1. grid (Mm/2048, 16).
// ---------------------------------------------------------------------------
template <int HASP>
__global__ __launch_bounds__(256) void k_gru_t(
    const float* __restrict__ hg, const float* __restrict__ hp,
    const float* __restrict__ WTl,   // [64][384] k-major: 0..191 ih, 192..383 hh
    const float* __restrict__ bih, const float* __restrict__ bhh,
    float* __restrict__ hout) {
  __shared__ float w[64 * 24];       // [k][g][c], g: 0..2 ih(r,z,n), 3..5 hh(r,z,n)
  int tid = threadIdx.x;
  int j0 = blockIdx.y << 2;
  for (int idx = tid; idx < 64 * 24; idx += 256) {
    int k = idx / 24, rem = idx % 24;
    int gg = rem >> 2, c = rem & 3;
    int col = ((gg < 3) ? (gg << 6) : (192 + ((gg - 3) << 6))) + j0 + c;
    w[idx] = WTl[k * 384 + col];
  }
  __syncthreads();
  int rbase = (blockIdx.x << 11) + tid;
  float aR[8][4], aZ[8][4], aNi[8][4], aNh[8][4];
#pragma unroll
  for (int c = 0; c < 4; ++c) {
    float bR = bih[j0 + c] + bhh[j0 + c];
    float bZ = bih[64 + j0 + c] + bhh[64 + j0 + c];
    float bNi = bih[128 + j0 + c];
    float bNh = bhh[128 + j0 + c];
#pragma unroll
    for (int i = 0; i < 8; ++i) {
      aR[i][c] = bR; aZ[i][c] = bZ; aNi[i][c] = bNi; aNh[i][c] = bNh;
    }
  }
#pragma unroll 1
  for (int kc = 0; kc < 16; ++kc) {
    float4 g4[8], p4[8];
#pragma unroll
    for (int i = 0; i < 8; ++i) {
      size_t rb = ((size_t)(rbase + (i << 8)) << 6) + 4 * kc;
      g4[i] = *(const float4*)(hg + rb);
      if (HASP) p4[i] = *(const float4*)(hp + rb);
    }
#pragma unroll
    for (int q = 0; q < 4; ++q) {
      const float* wk = w + (4 * kc + q) * 24;
      float4 wri = *(const float4*)(wk);
      float4 wzi = *(const float4*)(wk + 4);
      float4 wni = *(const float4*)(wk + 8);
      float4 wrh, wzh, wnh;
      if (HASP) {
        wrh = *(const float4*)(wk + 12);
        wzh = *(const float4*)(wk + 16);
        wnh = *(const float4*)(wk + 20);
      }
#pragma unroll
      for (int i = 0; i < 8; ++i) {
        float xg = ((const float*)&g4[i])[q];
        aR[i][0]  = fmaf(xg, wri.x, aR[i][0]);
        aR[i][1]  = fmaf(xg, wri.y, aR[i][1]);
        aR[i][2]  = fmaf(xg, wri.z, aR[i][2]);
        aR[i][3]  = fmaf(xg, wri.w, aR[i][3]);
        aZ[i][0]  = fmaf(xg, wzi.x, aZ[i][0]);
        aZ[i][1]  = fmaf(xg, wzi.y, aZ[i][1]);
        aZ[i][2]  = fmaf(xg, wzi.z, aZ[i][2]);
        aZ[i][3]  = fmaf(xg, wzi.w, aZ[i][3]);
        aNi[i][0] = fmaf(xg, wni.x, aNi[i][0]);
        aNi[i][1] = fmaf(xg, wni.y, aNi[i][1]);
        aNi[i][2] = fmaf(xg, wni.z, aNi[i][2]);
        aNi[i][3] = fmaf(xg, wni.w, aNi[i][3]);
        if (HASP) {
          float xh = ((const float*)&p4[i])[q];
          aR[i][0]  = fmaf(xh, wrh.x, aR[i][0]);
          aR[i][1]  = fmaf(xh, wrh.y, aR[i][1]);
          aR[i][2]  = fmaf(xh, wrh.z, aR[i][2]);
          aR[i][3]  = fmaf(xh, wrh.w, aR[i][3]);
          aZ[i][0]  = fmaf(xh, wzh.x, aZ[i][0]);
          aZ[i][1]  = fmaf(xh, wzh.y, aZ[i][1]);
          aZ[i][2]  = fmaf(xh, wzh.z, aZ[i][2]);
          aZ[i][3]  = fmaf(xh, wzh.w, aZ[i][3]);
          aNh[i][0] = fmaf(xh, wnh.x, aNh[i][0]);
          aNh[i][1] = fmaf(xh, wnh.y, aNh[i][1]);
          aNh[i][2] = fmaf(xh, wnh.z, aNh[i][2]);
          aNh[i][3] = fmaf(xh, wnh.w, aNh[i][3]);
        }
      }
    }
  }
#pragma unroll
  for (int i = 0; i < 8; ++i) {
    size_t rb = ((size_t)(rbase + (i << 8)) << 6) + j0;
    float4 hv = make_float4(0.f, 0.f, 0.f, 0.f);
    if (HASP) hv = *(const float4*)(hp + rb);
    float o[4];
#pragma unroll
    for (int c = 0; c < 4; ++c) {
      float rg = sigf(aR[i][c]);
      float zg = sigf(aZ[i][c]);
      float ng = tanhfast(aNi[i][c] + rg * aNh[i][c]);
      float hpv = ((const float*)&hv)[c];
      o[c] = (1.f - zg) * ng + zg * hpv;
    }
    *(float4*)(hout + rb) = make_float4(o[0], o[1], o[2], o[3]);
  }
}

// ---------------------------------------------------------------------------
__global__ __launch_bounds__(256) void k_heads(
    const float* __restrict__ Xb,
    const float* __restrict__ oW1, const float* __restrict__ ob1,
    const float* __restrict__ oW2, const float* __restrict__ ob2,
    const float* __restrict__ dW1, const float* __restrict__ db1,
    const float* __restrict__ dW2, const float* __restrict__ db2,
    float* __restrict__ out) {
  __shared__ float w1o[Hh * HB2], w1d[Hh * HB2];
  __shared__ float w2o[HB2], w2d[HB2], b1o[HB2], b1d[HB2];
  int tid = threadIdx.x;
  for (int idx = tid; idx < Hh * HB2; idx += 256) { w1o[idx] = oW1[idx]; w1d[idx] = dW1[idx]; }
  if (tid < HB2) { w2o[tid] = oW2[tid]; w2d[tid] = dW2[tid]; b1o[tid] = ob1[tid]; b1d[tid] = db1[tid]; }
  __syncthreads();
  int r = blockIdx.x * 256 + tid;
  int b = r >> 11, n = r & (Nn - 1);
  const float* xrow = Xb + (((size_t)b * Ss + (Ss - 1)) * Nn + n) * Hh;
  float x[Hh];
  const float4* xp = (const float4*)xrow;
#pragma unroll
  for (int q = 0; q < Hh / 4; ++q) {
    float4 v = xp[q];
    x[4*q] = v.x; x[4*q+1] = v.y; x[4*q+2] = v.z; x[4*q+3] = v.w;
  }
  float acco = ob2[0], accd = db2[0];
  for (int j = 0; j < HB2; ++j) {
    float ho = b1o[j], hd = b1d[j];
#pragma unroll
    for (int k = 0; k < Hh; ++k) {
      ho += x[k] * w1o[k * HB2 + j];
      hd += x[k] * w1d[k * HB2 + j];
    }
    acco += fmaxf(ho, 0.f) * w2o[j];
    accd += fmaxf(hd, 0.f) * w2d[j];
  }
  out[r] = acco;
  out[Bb * Nn + r] = accd;
}

// ---------------------------------------------------------------------------
extern "C" void kernel_launch(void* const* d_in, const int* in_sizes, int n_in,
                              void* d_out, int out_size, void* d_ws, size_t ws_size,
                              hipStream_t stream) {
  const float* x   = (const float*)d_in[0];
  const int*   ei  = (const int*)d_in[1];
  const float* ea  = (const float*)d_in[2];
  const float* Wp  = (const float*)d_in[3];
  const float* bp  = (const float*)d_in[4];
  const float* Wl  = (const float*)d_in[5];
  const float* bl  = (const float*)d_in[6];
  const float* Wr  = (const float*)d_in[7];
  const float* br  = (const float*)d_in[8];
  const float* We  = (const float*)d_in[9];
  const float* att = (const float*)d_in[10];
  const float* gb  = (const float*)d_in[11];
  const float* Wih = (const float*)d_in[12];
  const float* Whh = (const float*)d_in[13];
  const float* bih = (const float*)d_in[14];
  const float* bhh = (const float*)d_in[15];
  const float* oW1 = (const float*)d_in[16];
  const float* ob1 = (const float*)d_in[17];
  const float* oW2 = (const float*)d_in[18];
  const float* ob2 = (const float*)d_in[19];
  const float* dW1 = (const float*)d_in[20];
  const float* db1 = (const float*)d_in[21];
  const float* dW2 = (const float*)d_in[22];
  const float* db2 = (const float*)d_in[23];
  float* out = (float*)d_out;

  // workspace layout (floats)
  float* f    = (float*)d_ws;
  float* Xb   = f;                          // 131072*64
  float* XLb  = Xb  + (size_t)RTOT * Hh;    // 131072*64
  float* XRb  = XLb + (size_t)RTOT * Hh;    // 131072*64 (hg after k_gat)
  float* EPc  = XRb + (size_t)RTOT * Hh;    // 18432*64 (CSR order)
  float* WTb  = EPc + (size_t)E2c * Hh;     // 2*64*384
  float* cntF = WTb + 2 * 64 * 384;         // 2048
  float* loopA = cntF + Nn;                 // 2048*8
  int*   fillI = (int*)(loopA + Nn * EFf);  // 2048
  int*   offs  = fillI + Nn;                // 2049 (+pad)
  int*   posOf = offs + 2052;               // 18432
  int*   srcA  = posOf + E2c;               // 18432

  hipMemsetAsync(cntF, 0, (size_t)(Nn + Nn * EFf + Nn) * 4, stream);

  k_loop_accum<<<dim3(Ee * EFf / 256), 256, 0, stream>>>(ei, ea, cntF, loopA);
  k_loop_div<<<dim3(Nn * EFf / 256), 256, 0, stream>>>(loopA, cntF);
  k_scan<<<1, 256, 0, stream>>>(cntF, offs);
  k_scatter<<<dim3((E2c + 255) / 256), 256, 0, stream>>>(ei, offs, fillI, posOf, srcA);
  k_wtr<<<dim3(2 * 64 * 384 / 256), 256, 0, stream>>>(Wih, Whh, WTb);

  // X = x @ Wp + bp
  k_proj<<<dim3(RTOT / 2048, 8), 256, 0, stream>>>(x, Wp, bp, Xb);

  for (int l = 0; l < 2; ++l) {
    k_ep<<<dim3(E2c * Hh / 256), 256, 0, stream>>>(
        ea, loopA, We + (size_t)l * EFf * Hh, posOf, EPc);
    k_xlr<<<dim3(RTOT / 2048, 8), 256, 0, stream>>>(
        Xb, Wl + (size_t)l * Hh * Hh, bl + (size_t)l * Hh,
        Wr + (size_t)l * Hh * Hh, br + (size_t)l * Hh, XLb, XRb);
    k_gat<<<dim3(RTOT * Hh / 256), 256, 0, stream>>>(
        XLb, XRb, EPc, offs, srcA, att + (size_t)l * Hh, gb + (size_t)l * Hh);
    const float* WTl = WTb + (size_t)l * 64 * 384;
    const float* bih_l = bih + (size_t)l * 192;
    const float* bhh_l = bhh + (size_t)l * 192;
    for (int t = 0; t < Bb; ++t) {
      const float* hg_t = XRb + (size_t)t * Mm * Hh;
      float* h_out = Xb + (size_t)t * Mm * Hh;
      if (t == 0) {
        k_gru_t<0><<<dim3(Mm / 2048, 16), 256, 0, stream>>>(
            hg_t, nullptr, WTl, bih_l, bhh_l, h_out);
      } else {
        const float* h_prev = Xb + (size_t)(t - 1) * Mm * Hh;
        k_gru_t<1><<<dim3(Mm / 2048, 16), 256, 0, stream>>>(
            hg_t, h_prev, WTl, bih_l, bhh_l, h_out);
      }
    }
  }

  k_heads<<<dim3(Bb * Nn / 256), 256, 0, stream>>>(
      Xb, oW1, ob1, oW2, ob2, dW1, db1, dW2, db2, out);
}

// Round 7
// 756.618 us; speedup vs baseline: 1.4148x; 1.4148x over previous
//
#include <hip/hip_runtime.h>
#include <math.h>

#define Bb   4
#define Ss   16
#define Nn   2048
#define Ff   32
#define Ee   16384
#define EFf  8
#define Hh   64
#define HB2  32
#define E2c  (Ee + Nn)          // 18432
#define RTOT (Bb*Ss*Nn)         // 131072
#define Mm   (Ss*Nn)            // 32768

__device__ __forceinline__ float sigf(float x) { return 1.f / (1.f + __expf(-x)); }
__device__ __forceinline__ float tanhfast(float x) { return 2.f / (1.f + __expf(-2.f * x)) - 1.f; }
__device__ __forceinline__ float rlanef(float v, int l) {
  return __int_as_float(__builtin_amdgcn_readlane(__float_as_int(v), l));
}

// 64-lane sum, all-DPP (zero DS): quad xor1/xor2, row_ror4/8, bcast15/31,
// total lands in lane 63 -> readlane. Returns wave-uniform value.
__device__ __forceinline__ float rsum64u(float v) {
  int x;
  x = __builtin_amdgcn_update_dpp(0, __float_as_int(v), 0xB1, 0xF, 0xF, true);   // quad_perm xor1
  v += __int_as_float(x);
  x = __builtin_amdgcn_update_dpp(0, __float_as_int(v), 0x4E, 0xF, 0xF, true);   // quad_perm xor2
  v += __int_as_float(x);
  x = __builtin_amdgcn_update_dpp(0, __float_as_int(v), 0x124, 0xF, 0xF, true);  // row_ror:4
  v += __int_as_float(x);
  x = __builtin_amdgcn_update_dpp(0, __float_as_int(v), 0x128, 0xF, 0xF, true);  // row_ror:8
  v += __int_as_float(x);
  x = __builtin_amdgcn_update_dpp(0, __float_as_int(v), 0x142, 0xF, 0xF, true);  // row_bcast:15
  v += __int_as_float(x);
  x = __builtin_amdgcn_update_dpp(0, __float_as_int(v), 0x143, 0xF, 0xF, true);  // row_bcast:31
  v += __int_as_float(x);
  return __int_as_float(__builtin_amdgcn_readlane(__float_as_int(v), 63));
}

// ---------------------------------------------------------------------------
__global__ __launch_bounds__(256) void k_loop_accum(
    const int* __restrict__ ei, const float* __restrict__ ea,
    float* __restrict__ cntF, float* __restrict__ loopA) {
  int idx = blockIdx.x * 256 + threadIdx.x;
  int e = idx >> 3, j = idx & 7;
  int d = ei[Ee + e];
  atomicAdd(&loopA[d * EFf + j], ea[idx]);
  if (j == 0) atomicAdd(&cntF[d], 1.0f);
}

__global__ __launch_bounds__(256) void k_loop_div(
    float* __restrict__ loopA, const float* __restrict__ cntF) {
  int idx = blockIdx.x * 256 + threadIdx.x;
  loopA[idx] /= fmaxf(cntF[idx >> 3], 1.0f);
}

// ---------------------------------------------------------------------------
__global__ __launch_bounds__(256) void k_scan(
    const float* __restrict__ cntF, int* __restrict__ offs) {
  __shared__ int partial[256];
  int tid = threadIdx.x;
  int base = tid * 8;
  int vals[8];
  int s = 0;
  for (int i = 0; i < 8; ++i) {
    int c = (int)cntF[base + i] + 1;
    vals[i] = c;
    s += c;
  }
  partial[tid] = s;
  __syncthreads();
  for (int off = 1; off < 256; off <<= 1) {
    int v = partial[tid];
    int add = (tid >= off) ? partial[tid - off] : 0;
    __syncthreads();
    partial[tid] = v + add;
    __syncthreads();
  }
  int run = (tid == 0) ? 0 : partial[tid - 1];
  for (int i = 0; i < 8; ++i) {
    offs[base + i] = run;
    run += vals[i];
  }
  if (tid == 255) offs[Nn] = run;
}

__global__ __launch_bounds__(256) void k_scatter(
    const int* __restrict__ ei, const int* __restrict__ offs,
    int* __restrict__ fillI, int* __restrict__ posOf, int* __restrict__ srcA) {
  int e = blockIdx.x * 256 + threadIdx.x;
  if (e >= E2c) return;
  int d = (e < Ee) ? ei[Ee + e] : (e - Ee);
  int s = (e < Ee) ? ei[e]      : (e - Ee);
  int pos = offs[d] + atomicAdd(&fillI[d], 1);
  posOf[e] = pos;
  srcA[pos] = s;
}

// ---------------------------------------------------------------------------
__global__ __launch_bounds__(256) void k_wtr(
    const float* __restrict__ Wih, const float* __restrict__ Whh,
    float* __restrict__ WT) {
  int idx = blockIdx.x * 256 + threadIdx.x;   // 2*64*384
  int l = idx / (64 * 384);
  int k = (idx / 384) & 63;
  int j = idx % 384;
  float v = (j < 192) ? Wih[((size_t)l * 192 + j) * 64 + k]
                      : Whh[((size_t)l * 192 + (j - 192)) * 64 + k];
  WT[idx] = v;
}

// ---------------------------------------------------------------------------
__global__ __launch_bounds__(256) void k_ep(
    const float* __restrict__ ea, const float* __restrict__ loopA,
    const float* __restrict__ We, const int* __restrict__ posOf,
    float* __restrict__ EPc) {
  __shared__ float wlds[EFf * Hh];
  int tid = threadIdx.x;
  if (tid < EFf * Hh) wlds[tid] = We[tid];
  if (tid + 256 < EFf * Hh) wlds[tid + 256] = We[tid + 256];
  __syncthreads();
  int idx = blockIdx.x * 256 + tid;
  int e = idx >> 6, j = idx & 63;
  const float* a = (e < Ee) ? (ea + (size_t)e * EFf) : (loopA + (size_t)(e - Ee) * EFf);
  float acc = 0.f;
#pragma unroll
  for (int k = 0; k < EFf; ++k) acc += a[k] * wlds[k * Hh + j];
  EPc[(((size_t)posOf[e]) << 6) + j] = acc;
}

// ---------------------------------------------------------------------------
// proj (R5 version): thread = 2 rows x 16-col slice. grid (RTOT/512, 4).
// ---------------------------------------------------------------------------
__global__ __launch_bounds__(256) void k_proj(
    const float* __restrict__ X, const float* __restrict__ Wp,
    const float* __restrict__ bp, float* __restrict__ Out) {
  __shared__ float w[32 * 16];
  int tid = threadIdx.x;
  int j0 = blockIdx.y << 4;
  for (int idx = tid; idx < 32 * 16; idx += 256)
    w[idx] = Wp[((idx >> 4) << 6) + j0 + (idx & 15)];
  __syncthreads();
  int r0 = (blockIdx.x << 9) + tid;   // rows r0 and r0+256
  float acc[2][16];
#pragma unroll
  for (int jj = 0; jj < 16; ++jj) { float b = bp[j0 + jj]; acc[0][jj] = b; acc[1][jj] = b; }
  const float* x0 = X + ((size_t)r0 << 5);
  const float* x1 = x0 + (256 << 5);
  for (int kc = 0; kc < 8; ++kc) {
    float4 a0 = *(const float4*)(x0 + 4 * kc);
    float4 a1 = *(const float4*)(x1 + 4 * kc);
    float a0a[4] = {a0.x, a0.y, a0.z, a0.w};
    float a1a[4] = {a1.x, a1.y, a1.z, a1.w};
#pragma unroll
    for (int q = 0; q < 4; ++q) {
      const float4* wp4 = (const float4*)(w + ((4 * kc + q) << 4));
#pragma unroll
      for (int q4 = 0; q4 < 4; ++q4) {
        float4 wv = wp4[q4];
        acc[0][4*q4+0] = fmaf(a0a[q], wv.x, acc[0][4*q4+0]);
        acc[0][4*q4+1] = fmaf(a0a[q], wv.y, acc[0][4*q4+1]);
        acc[0][4*q4+2] = fmaf(a0a[q], wv.z, acc[0][4*q4+2]);
        acc[0][4*q4+3] = fmaf(a0a[q], wv.w, acc[0][4*q4+3]);
        acc[1][4*q4+0] = fmaf(a1a[q], wv.x, acc[1][4*q4+0]);
        acc[1][4*q4+1] = fmaf(a1a[q], wv.y, acc[1][4*q4+1]);
        acc[1][4*q4+2] = fmaf(a1a[q], wv.z, acc[1][4*q4+2]);
        acc[1][4*q4+3] = fmaf(a1a[q], wv.w, acc[1][4*q4+3]);
      }
    }
  }
#pragma unroll
  for (int rr = 0; rr < 2; ++rr) {
    float* op = Out + (((size_t)(r0 + 256 * rr)) << 6) + j0;
#pragma unroll
    for (int q4 = 0; q4 < 4; ++q4)
      *(float4*)(op + 4 * q4) = make_float4(acc[rr][4*q4], acc[rr][4*q4+1], acc[rr][4*q4+2], acc[rr][4*q4+3]);
  }
}

// ---------------------------------------------------------------------------
// Fused XL/XR, lane=column: lane j owns output col j. Thread = 16 rows.
// A row = 1 coalesced dword load (lane=k), extracted via readlane (SGPR op).
// W in LDS [k][2][64], per-lane stride-1 reads (2-way bank = free).
// Per wave per k: 16 readlane + 32 FMA = 96 cyc vs 2 b32 DS ~12 cyc = 8:1.
// grid RTOT/64. block = 4 waves x 16 rows.
// ---------------------------------------------------------------------------
__global__ __launch_bounds__(256) void k_xlr(
    const float* __restrict__ X,
    const float* __restrict__ Wl_, const float* __restrict__ bl_,
    const float* __restrict__ Wr_, const float* __restrict__ br_,
    float* __restrict__ XL, float* __restrict__ XR) {
  __shared__ float w[64 * 128];    // [k][0:wl,1:wr][64]
  int tid = threadIdx.x;
  int lane = tid & 63;
  // stage W: w[k*128 + lane] = Wl[k*64+lane]; w[k*128+64+lane] = Wr[...]
  for (int i = tid; i < 64 * 64; i += 256) {
    int k = i >> 6, c = i & 63;
    w[(k << 7) + c] = Wl_[i];
    w[(k << 7) + 64 + c] = Wr_[i];
  }
  __syncthreads();
  int rowbase = (blockIdx.x << 6) + ((tid >> 6) << 4);
  float vX[16];
#pragma unroll
  for (int r = 0; r < 16; ++r)
    vX[r] = X[(((size_t)(rowbase + r)) << 6) + lane];
  float bL = bl_[lane], bR = br_[lane];
  float accL[16], accR[16];
#pragma unroll
  for (int r = 0; r < 16; ++r) { accL[r] = bL; accR[r] = bR; }
#pragma unroll 4
  for (int k = 0; k < 64; ++k) {
    float wlv = w[(k << 7) + lane];
    float wrv = w[(k << 7) + 64 + lane];
#pragma unroll
    for (int r = 0; r < 16; ++r) {
      float xv = rlanef(vX[r], k);
      accL[r] = fmaf(xv, wlv, accL[r]);
      accR[r] = fmaf(xv, wrv, accR[r]);
    }
  }
#pragma unroll
  for (int r = 0; r < 16; ++r) {
    size_t ob = (((size_t)(rowbase + r)) << 6) + lane;
    XL[ob] = accL[r];
    XR[ob] = accR[r];
  }
}

// ---------------------------------------------------------------------------
// GATv2: wave per (g,d), lane = h. DS-free inner loop: DPP reduce + readlane
// broadcast of src offsets. 8-wide masked chunks.
// ---------------------------------------------------------------------------
__global__ __launch_bounds__(256) void k_gat(
    const float* __restrict__ XL, float* __restrict__ XR_HG,
    const float* __restrict__ EPc, const int* __restrict__ offs,
    const int* __restrict__ srcA,
    const float* __restrict__ att, const float* __restrict__ gbl) {
  int gw = (blockIdx.x * 256 + threadIdx.x) >> 6;
  int lane = threadIdx.x & 63;
  int g = gw >> 11;
  int d = gw & (Nn - 1);
  float attv = att[lane];
  float gbv = gbl[lane];
  size_t rowbase = ((size_t)gw) << 6;
  float xr = XR_HG[rowbase + lane];
  int p0 = offs[d], p1 = offs[d + 1];
  int nE = p1 - p0;
  int nE4 = nE < 64 ? nE : 64;
  int soff = 0;
  if (lane < nE4) soff = srcA[p0 + lane] << 8;           // byte offset of src row
  const char* XLg = (const char*)(XL + (((size_t)g * Nn) << 6)) + (lane << 2);
  const char* EPp = (const char*)(EPc + (((size_t)p0) << 6)) + (lane << 2);
  float Ssum = 0.f, acc = 0.f;
  int nCh = (nE4 + 7) >> 3;
  for (int c = 0; c < nCh; ++c) {
    int p = c << 3;
    float xl[8], vv[8];
#pragma unroll
    for (int u = 0; u < 8; ++u) {
      int pu = p + u;
      int pc = pu < nE4 ? pu : nE4 - 1;                  // clamp (masked later)
      int so = __builtin_amdgcn_readlane(soff, pc);      // uniform, no DS
      xl[u] = *(const float*)(XLg + so);
      float ep = *(const float*)(EPp + (pc << 8));
      float m = xl[u] + xr + ep;
      m = fmaxf(m, 0.2f * m);                            // leaky_relu(0.2)
      vv[u] = m * attv;
    }
#pragma unroll
    for (int u = 0; u < 8; ++u) vv[u] = rsum64u(vv[u]);
#pragma unroll
    for (int u = 0; u < 8; ++u) {
      float v = (p + u < nE4) ? vv[u] : -1e30f;
      float w = __expf(v);
      Ssum += w;
      acc = fmaf(w, xl[u], acc);
    }
  }
  for (int p = 64; p < nE; ++p) {                        // pathological tail
    int s = srcA[p0 + p];
    float xlv = *(const float*)(XLg + (s << 8));
    float ep = *(const float*)(EPp + (p << 8));
    float m = xlv + xr + ep; m = fmaxf(m, 0.2f * m);
    float w = __expf(rsum64u(m * attv));
    Ssum += w; acc = fmaf(w, xlv, acc);
  }
  XR_HG[rowbase + lane] = acc / Ssum + gbv;
}

// ---------------------------------------------------------------------------
// Per-t fused GRU, lane=column: lane j owns h-col j (all gates). Thread = 16
// rows; acc = aR,aZ,aNi,aNh[16] = 64 VGPR. A rows = coalesced dword loads
// (lane=k), extracted via readlane; hp register doubles as epilogue operand
// (lane=k == lane=col). W [k][6][64] staged in 2 halves of 48 KB LDS.
// Per wave per k: 32 readlane + 96 FMA = 256 cyc vs 6 b32 DS ~35 cyc = 7:1.
// grid Mm/64.
// ---------------------------------------------------------------------------
template <int HASP>
__global__ __launch_bounds__(256) void k_gru_t(
    const float* __restrict__ hg, const float* __restrict__ hp,
    const float* __restrict__ WTl,   // [64][384] k-major: 0..191 ih(r,z,n), 192..383 hh
    const float* __restrict__ bih, const float* __restrict__ bhh,
    float* __restrict__ hout) {
  __shared__ float w[32 * 384];      // half of WT: [k][g][64]
  int tid = threadIdx.x;
  int lane = tid & 63;
  int rowbase = (blockIdx.x << 6) + ((tid >> 6) << 4);

  float vHg[16], vHp[16];
#pragma unroll
  for (int r = 0; r < 16; ++r) {
    size_t rb = (((size_t)(rowbase + r)) << 6) + lane;
    vHg[r] = hg[rb];
    if (HASP) vHp[r] = hp[rb];
  }
  float aR[16], aZ[16], aNi[16], aNh[16];
  {
    float bR = bih[lane] + bhh[lane];
    float bZ = bih[64 + lane] + bhh[64 + lane];
    float bNi = bih[128 + lane];
    float bNh = bhh[128 + lane];
#pragma unroll
    for (int r = 0; r < 16; ++r) { aR[r] = bR; aZ[r] = bZ; aNi[r] = bNi; aNh[r] = bNh; }
  }

#pragma unroll 1
  for (int half = 0; half < 2; ++half) {
    if (half) __syncthreads();
    {
      const float4* src = (const float4*)(WTl + half * 32 * 384);
      float4* dst = (float4*)w;
      for (int i = tid; i < 32 * 96; i += 256) dst[i] = src[i];
    }
    __syncthreads();
#pragma unroll 4
    for (int kk = 0; kk < 32; ++kk) {
      const float* wk = w + kk * 384;
      float wri = wk[lane];
      float wzi = wk[64 + lane];
      float wni = wk[128 + lane];
      float wrh, wzh, wnh;
      if (HASP) {
        wrh = wk[192 + lane];
        wzh = wk[256 + lane];
        wnh = wk[320 + lane];
      }
      int k = (half << 5) + kk;
#pragma unroll
      for (int r = 0; r < 16; ++r) {
        float xg = rlanef(vHg[r], k);
        aR[r]  = fmaf(xg, wri, aR[r]);
        aZ[r]  = fmaf(xg, wzi, aZ[r]);
        aNi[r] = fmaf(xg, wni, aNi[r]);
        if (HASP) {
          float xh = rlanef(vHp[r], k);
          aR[r]  = fmaf(xh, wrh, aR[r]);
          aZ[r]  = fmaf(xh, wzh, aZ[r]);
          aNh[r] = fmaf(xh, wnh, aNh[r]);
        }
      }
    }
  }

#pragma unroll
  for (int r = 0; r < 16; ++r) {
    float rg = sigf(aR[r]);
    float zg = sigf(aZ[r]);
    float ng = tanhfast(aNi[r] + rg * aNh[r]);
    float hv = HASP ? vHp[r] : 0.f;
    hout[(((size_t)(rowbase + r)) << 6) + lane] = (1.f - zg) * ng + zg * hv;
  }
}

// ---------------------------------------------------------------------------
__global__ __launch_bounds__(256) void k_heads(
    const float* __restrict__ Xb,
    const float* __restrict__ oW1, const float* __restrict__ ob1,
    const float* __restrict__ oW2, const float* __restrict__ ob2,
    const float* __restrict__ dW1, const float* __restrict__ db1,
    const float* __restrict__ dW2, const float* __restrict__ db2,
    float* __restrict__ out) {
  __shared__ float w1o[Hh * HB2], w1d[Hh * HB2];
  __shared__ float w2o[HB2], w2d[HB2], b1o[HB2], b1d[HB2];
  int tid = threadIdx.x;
  for (int idx = tid; idx < Hh * HB2; idx += 256) { w1o[idx] = oW1[idx]; w1d[idx] = dW1[idx]; }
  if (tid < HB2) { w2o[tid] = oW2[tid]; w2d[tid] = dW2[tid]; b1o[tid] = ob1[tid]; b1d[tid] = db1[tid]; }
  __syncthreads();
  int r = blockIdx.x * 256 + tid;
  int b = r >> 11, n = r & (Nn - 1);
  const float* xrow = Xb + (((size_t)b * Ss + (Ss - 1)) * Nn + n) * Hh;
  float x[Hh];
  const float4* xp = (const float4*)xrow;
#pragma unroll
  for (int q = 0; q < Hh / 4; ++q) {
    float4 v = xp[q];
    x[4*q] = v.x; x[4*q+1] = v.y; x[4*q+2] = v.z; x[4*q+3] = v.w;
  }
  float acco = ob2[0], accd = db2[0];
  for (int j = 0; j < HB2; ++j) {
    float ho = b1o[j], hd = b1d[j];
#pragma unroll
    for (int k = 0; k < Hh; ++k) {
      ho += x[k] * w1o[k * HB2 + j];
      hd += x[k] * w1d[k * HB2 + j];
    }
    acco += fmaxf(ho, 0.f) * w2o[j];
    accd += fmaxf(hd, 0.f) * w2d[j];
  }
  out[r] = acco;
  out[Bb * Nn + r] = accd;
}

// ---------------------------------------------------------------------------
extern "C" void kernel_launch(void* const* d_in, const int* in_sizes, int n_in,
                              void* d_out, int out_size, void* d_ws, size_t ws_size,
                              hipStream_t stream) {
  const float* x   = (const float*)d_in[0];
  const int*   ei  = (const int*)d_in[1];
  const float* ea  = (const float*)d_in[2];
  const float* Wp  = (const float*)d_in[3];
  const float* bp  = (const float*)d_in[4];
  const float* Wl  = (const float*)d_in[5];
  const float* bl  = (const float*)d_in[6];
  const float* Wr  = (const float*)d_in[7];
  const float* br  = (const float*)d_in[8];
  const float* We  = (const float*)d_in[9];
  const float* att = (const float*)d_in[10];
  const float* gb  = (const float*)d_in[11];
  const float* Wih = (const float*)d_in[12];
  const float* Whh = (const float*)d_in[13];
  const float* bih = (const float*)d_in[14];
  const float* bhh = (const float*)d_in[15];
  const float* oW1 = (const float*)d_in[16];
  const float* ob1 = (const float*)d_in[17];
  const float* oW2 = (const float*)d_in[18];
  const float* ob2 = (const float*)d_in[19];
  const float* dW1 = (const float*)d_in[20];
  const float* db1 = (const float*)d_in[21];
  const float* dW2 = (const float*)d_in[22];
  const float* db2 = (const float*)d_in[23];
  float* out = (float*)d_out;

  // workspace layout (floats)
  float* f    = (float*)d_ws;
  float* Xb   = f;                          // 131072*64
  float* XLb  = Xb  + (size_t)RTOT * Hh;    // 131072*64
  float* XRb  = XLb + (size_t)RTOT * Hh;    // 131072*64 (hg after k_gat)
  float* EPc  = XRb + (size_t)RTOT * Hh;    // 18432*64 (CSR order)
  float* WTb  = EPc + (size_t)E2c * Hh;     // 2*64*384
  float* cntF = WTb + 2 * 64 * 384;         // 2048
  float* loopA = cntF + Nn;                 // 2048*8
  int*   fillI = (int*)(loopA + Nn * EFf);  // 2048
  int*   offs  = fillI + Nn;                // 2049 (+pad)
  int*   posOf = offs + 2052;               // 18432
  int*   srcA  = posOf + E2c;               // 18432

  hipMemsetAsync(cntF, 0, (size_t)(Nn + Nn * EFf + Nn) * 4, stream);

  k_loop_accum<<<dim3(Ee * EFf / 256), 256, 0, stream>>>(ei, ea, cntF, loopA);
  k_loop_div<<<dim3(Nn * EFf / 256), 256, 0, stream>>>(loopA, cntF);
  k_scan<<<1, 256, 0, stream>>>(cntF, offs);
  k_scatter<<<dim3((E2c + 255) / 256), 256, 0, stream>>>(ei, offs, fillI, posOf, srcA);
  k_wtr<<<dim3(2 * 64 * 384 / 256), 256, 0, stream>>>(Wih, Whh, WTb);

  // X = x @ Wp + bp
  k_proj<<<dim3(RTOT / 512, 4), 256, 0, stream>>>(x, Wp, bp, Xb);

  for (int l = 0; l < 2; ++l) {
    k_ep<<<dim3(E2c * Hh / 256), 256, 0, stream>>>(
        ea, loopA, We + (size_t)l * EFf * Hh, posOf, EPc);
    k_xlr<<<dim3(RTOT / 64), 256, 0, stream>>>(
        Xb, Wl + (size_t)l * Hh * Hh, bl + (size_t)l * Hh,
        Wr + (size_t)l * Hh * Hh, br + (size_t)l * Hh, XLb, XRb);
    k_gat<<<dim3(RTOT * Hh / 256), 256, 0, stream>>>(
        XLb, XRb, EPc, offs, srcA, att + (size_t)l * Hh, gb + (size_t)l * Hh);
    const float* WTl = WTb + (size_t)l * 64 * 384;
    const float* bih_l = bih + (size_t)l * 192;
    const float* bhh_l = bhh + (size_t)l * 192;
    for (int t = 0; t < Bb; ++t) {
      const float* hg_t = XRb + (size_t)t * Mm * Hh;
      float* h_out = Xb + (size_t)t * Mm * Hh;
      if (t == 0) {
        k_gru_t<0><<<dim3(Mm / 64), 256, 0, stream>>>(
            hg_t, nullptr, WTl, bih_l, bhh_l, h_out);
      } else {
        const float* h_prev = Xb + (size_t)(t - 1) * Mm * Hh;
        k_gru_t<1><<<dim3(Mm / 64), 256, 0, stream>>>(
            hg_t, h_prev, WTl, bih_l, bhh_l, h_out);
      }
    }
  }

  k_heads<<<dim3(Bb * Nn / 256), 256, 0, stream>>>(
      Xb, oW1, ob1, oW2, ob2, dW1, db1, dW2, db2, out);
}